// Round 3
// baseline (470.519 us; speedup 1.0000x reference)
//
#include <hip/hip_runtime.h>
#include <hip/hip_bf16.h>
#include <cstdint>
#include <cstddef>

// Problem constants
#define HDIM 256
#define EDIM 512
#define NB   2
#define NSQ  512
#define NSK  512

typedef __bf16 bf16x8 __attribute__((ext_vector_type(8)));
typedef float  f32x4  __attribute__((ext_vector_type(4)));
typedef unsigned short u16x8 __attribute__((ext_vector_type(8)));

// Workspace layout (in ushort elements for the bf16 region)
#define OFF_W2F  0u          // 16 tiles x 8 s x 64 x 8  = 65536
#define OFF_W3F  65536u
#define OFF_WQEF 131072u     // 16 tiles x 16 s x 64 x 8 = 131072
#define OFF_WKEF 262144u
#define OFF_WCQ  393216u     // 32 tiles x 8 s x 64 x 8  = 131072
#define OFF_WCK  524288u
#define BF16_WS_END_BYTES 1310720u   // 655360 ushorts * 2

__device__ __forceinline__ unsigned short f2bf(float f) {
  unsigned u = __float_as_uint(f);
  u += 0x7fffu + ((u >> 16) & 1u);   // round-to-nearest-even
  return (unsigned short)(u >> 16);
}
// packed RNE f32x2 -> bf16x2 (v_cvt_pk_bf16_f32 on gfx950)
__device__ __forceinline__ ushort2 f2bf2(float x, float y) {
  __hip_bfloat162 h = __float22bfloat162_rn(float2{x, y});
  return *(ushort2*)&h;
}
__device__ __forceinline__ float relu_(float x) { return x > 0.f ? x : 0.f; }
__device__ __forceinline__ float softplus_(float x) {
  return fmaxf(x, 0.f) + log1pf(expf(-fabsf(x)));
}

// ---------------------------------------------------------------------------
// K1: shuffle fp32 weights into bf16 MFMA A-fragment order.
// A = W^T (A[n][k] = W[k][n]), layout [tile t][kstep s][lane][j=0..7]:
//   out[((t*S+s)*64+lane)*8 + j] = W[(s*32 + (lane>>4)*8 + j)*256 + t*16 + (lane&15)]
// ---------------------------------------------------------------------------
__global__ __launch_bounds__(64) void shuffle_weights(
    const float* __restrict__ Wqe, const float* __restrict__ Wke,
    const float* __restrict__ W1,  const float* __restrict__ Wv1,
    const float* __restrict__ W2,  const float* __restrict__ W3,
    unsigned short* __restrict__ wsb)
{
  const int bx = blockIdx.x;
  const int lane = threadIdx.x;
  const float* src; unsigned short* dst; int S; int idx;
  if      (bx <  128) { src = W2;          dst = wsb + OFF_W2F;           S = 8;  idx = bx;        }
  else if (bx <  256) { src = W3;          dst = wsb + OFF_W3F;           S = 8;  idx = bx - 128;  }
  else if (bx <  512) { src = Wqe;         dst = wsb + OFF_WQEF;          S = 16; idx = bx - 256;  }
  else if (bx <  768) { src = Wke;         dst = wsb + OFF_WKEF;          S = 16; idx = bx - 512;  }
  else if (bx <  896) { src = W1;          dst = wsb + OFF_WCQ;           S = 8;  idx = bx - 768;  }
  else if (bx < 1024) { src = Wv1;         dst = wsb + OFF_WCQ + 65536u;  S = 8;  idx = bx - 896;  }
  else if (bx < 1152) { src = W1 + 65536;  dst = wsb + OFF_WCK;           S = 8;  idx = bx - 1024; }
  else                { src = Wv1 + 65536; dst = wsb + OFF_WCK + 65536u;  S = 8;  idx = bx - 1152; }
  const int t = idx / S, s = idx % S;
  const int n  = t * 16 + (lane & 15);
  const int k0 = s * 32 + ((lane >> 4) << 3);
  unsigned short* o = dst + ((size_t)(t * S + s) * 64 + lane) * 8;
  #pragma unroll
  for (int j = 0; j < 8; j += 2) {
    ushort2 pp = f2bf2(src[(size_t)(k0 + j) * 256 + n], src[(size_t)(k0 + j + 1) * 256 + n]);
    *(ushort2*)&o[j] = pp;
  }
}

// ---------------------------------------------------------------------------
// K2: encoder + projections.
//  F  = relu(X @ We + be)               [rows, 256]
//  P  = F @ Wcat (+ b1|bv1 on q side)   [rows, 512]  (cols 0..255 = qp/kp, 256..511 = vq/vk)
// One block = 32 rows of one side. 64 blocks total.
// ---------------------------------------------------------------------------
__global__ __launch_bounds__(256) void encoder_kernel(
    const float* __restrict__ query, const float* __restrict__ key,
    const float* __restrict__ bqe,   const float* __restrict__ bke,
    const float* __restrict__ b1,    const float* __restrict__ bv1,
    const unsigned short* __restrict__ WqeF, const unsigned short* __restrict__ WkeF,
    const unsigned short* __restrict__ WcqF, const unsigned short* __restrict__ WckF,
    float* __restrict__ Pq, float* __restrict__ Pk)
{
  __shared__ unsigned short sX[32 * 520];   // X rows, bf16, pad +8
  __shared__ unsigned short sF[32 * 264];   // F rows, bf16, pad +8
  __shared__ float sBe[256];
  __shared__ float sBc[512];

  const int bx   = blockIdx.x;
  const int side = bx >> 5;          // 0 = q, 1 = k
  const int rt   = bx & 31;
  const int t    = threadIdx.x;

  const float* Xsrc = side ? key : query;
  const unsigned short* WeF = side ? WkeF : WqeF;
  const unsigned short* WcF = side ? WckF : WcqF;
  float* P = side ? Pk : Pq;

  {
    const int m = t >> 3, ch = t & 7;
    const int c0 = ch * 64;
    const float* xr = Xsrc + (size_t)(rt * 32 + m) * EDIM;
    #pragma unroll
    for (int cc = 0; cc < 64; cc += 4) {
      const int c = c0 + cc;
      float4 xv = *(const float4*)(xr + c);
      ushort2 lo = f2bf2(xv.x, xv.y);
      ushort2 hi = f2bf2(xv.z, xv.w);
      ushort4 xb; xb.x = lo.x; xb.y = lo.y; xb.z = hi.x; xb.w = hi.y;
      *(ushort4*)&sX[m * 520 + c] = xb;
    }
    sBe[t]       = side ? bke[t] : bqe[t];
    sBc[t]       = side ? 0.f : b1[t];
    sBc[256 + t] = side ? 0.f : bv1[t];
  }
  __syncthreads();

  const int wave = t >> 6, lane = t & 63;
  const int l15 = lane & 15, q4 = lane >> 4;

  // GEMM1e: D[n][m] = sum_k We[k][n] * X[m][k], K = 512 (16 k-steps)
  f32x4 acc1[4][2];
  #pragma unroll
  for (int ft = 0; ft < 4; ++ft)
    #pragma unroll
    for (int pt = 0; pt < 2; ++pt)
      acc1[ft][pt] = (f32x4){0.f, 0.f, 0.f, 0.f};

  for (int s = 0; s < 16; ++s) {
    bf16x8 af[4], bfr[2];
    #pragma unroll
    for (int ft = 0; ft < 4; ++ft) {
      const int tg = wave * 4 + ft;
      af[ft] = *(const bf16x8*)(WeF + ((size_t)(tg * 16 + s) * 64 + lane) * 8);
    }
    #pragma unroll
    for (int pt = 0; pt < 2; ++pt)
      bfr[pt] = *(const bf16x8*)&sX[(pt * 16 + l15) * 520 + s * 32 + q4 * 8];
    #pragma unroll
    for (int ft = 0; ft < 4; ++ft)
      #pragma unroll
      for (int pt = 0; pt < 2; ++pt)
        acc1[ft][pt] = __builtin_amdgcn_mfma_f32_16x16x32_bf16(af[ft], bfr[pt], acc1[ft][pt], 0, 0, 0);
  }

  // Epilogue 1: F = relu(D + be) -> bf16 LDS [m][n]
  #pragma unroll
  for (int ft = 0; ft < 4; ++ft) {
    const int tg = wave * 4 + ft;
    const int n0 = tg * 16 + q4 * 4;
    float4 b4 = *(const float4*)&sBe[n0];
    #pragma unroll
    for (int pt = 0; pt < 2; ++pt) {
      const int mr = pt * 16 + l15;
      f32x4 a = acc1[ft][pt];
      ushort2 lo = f2bf2(relu_(a[0] + b4.x), relu_(a[1] + b4.y));
      ushort2 hi = f2bf2(relu_(a[2] + b4.z), relu_(a[3] + b4.w));
      ushort4 h; h.x = lo.x; h.y = lo.y; h.z = hi.x; h.w = hi.y;
      *(ushort4*)&sF[mr * 264 + n0] = h;
    }
  }
  __syncthreads();

  // GEMM2e: P[n][m] = sum_k Wcat[k][n] * F[m][k], nout = 512 (32 tiles), K = 256 (8 steps)
  f32x4 acc2[8][2];
  #pragma unroll
  for (int ft = 0; ft < 8; ++ft)
    #pragma unroll
    for (int pt = 0; pt < 2; ++pt)
      acc2[ft][pt] = (f32x4){0.f, 0.f, 0.f, 0.f};

  for (int s = 0; s < 8; ++s) {
    bf16x8 af[8], bfr[2];
    #pragma unroll
    for (int ft = 0; ft < 8; ++ft) {
      const int tg = wave * 8 + ft;
      af[ft] = *(const bf16x8*)(WcF + ((size_t)(tg * 8 + s) * 64 + lane) * 8);
    }
    #pragma unroll
    for (int pt = 0; pt < 2; ++pt)
      bfr[pt] = *(const bf16x8*)&sF[(pt * 16 + l15) * 264 + s * 32 + q4 * 8];
    #pragma unroll
    for (int ft = 0; ft < 8; ++ft)
      #pragma unroll
      for (int pt = 0; pt < 2; ++pt)
        acc2[ft][pt] = __builtin_amdgcn_mfma_f32_16x16x32_bf16(af[ft], bfr[pt], acc2[ft][pt], 0, 0, 0);
  }

  // Epilogue 2: store P[row][n] = D + bias (fp32, no relu)
  #pragma unroll
  for (int ft = 0; ft < 8; ++ft) {
    const int tg = wave * 8 + ft;
    const int n0 = tg * 16 + q4 * 4;
    float4 bc = *(const float4*)&sBc[n0];
    #pragma unroll
    for (int pt = 0; pt < 2; ++pt) {
      const int mr = pt * 16 + l15;
      const int row = rt * 32 + mr;
      f32x4 a = acc2[ft][pt];
      float4 o;
      o.x = a[0] + bc.x; o.y = a[1] + bc.y; o.z = a[2] + bc.z; o.w = a[3] + bc.w;
      *(float4*)&P[(size_t)row * 512 + n0] = o;
    }
  }
}

// ---------------------------------------------------------------------------
// K3: fused pair kernel. One block = (b, q, 64 consecutive k). 256 threads.
// 4 waves; wave w owns n-tiles {4w..4w+3} (64 n-cols), all 64 m (acc 4x4).
// LDS XOR swizzle: 16B chunk c of row m stored at chunk c ^ (m&7).
//   X1 = relu(qp' + kp)            (LDS bf16, swizzled [64][256])
//   H1 = relu(X1 @ W2 + b2)        (MFMA transposed-out, same LDS)
//   H2 = relu(H1 @ W3 + b3)        (MFMA)
//   logit = H2 . Wf + bf
//   var   = softplus(relu(vq'+vk) . Wv2 + bv2)   (VALU during staging,
//           shfl-reduced over the 4 threads/row, stored immediately)
// ---------------------------------------------------------------------------
__global__ __launch_bounds__(256, 4) void pair_kernel(
    const float* __restrict__ Pq, const float* __restrict__ Pk,
    const unsigned short* __restrict__ W2F, const unsigned short* __restrict__ W3F,
    const float* __restrict__ b2, const float* __restrict__ b3,
    const float* __restrict__ Wf, const float* __restrict__ bfp,
    const float* __restrict__ Wv2, const float* __restrict__ bv2p,
    float* __restrict__ out)
{
  // Manual LDS carving; sRed aliases sB2 (dead after epilogue 1, and the
  // pre-GEMM2 barrier orders all sB2 reads before any sRed write).
  __shared__ __align__(16) unsigned char smem[35840];
  unsigned short* sXH = (unsigned short*)smem;        // 64*256 bf16 = 32768 B
  float* sB2   = (float*)(smem + 32768);              // 1024 B
  float* sB3   = (float*)(smem + 33792);              // 1024 B
  float* sWf   = (float*)(smem + 34816);              // 1024 B
  float* sRed  = (float*)(smem + 32768);              // 4*64*4 = 1024 B (alias sB2)

  const int kt = blockIdx.x, qy = blockIdx.y, bz = blockIdx.z;
  const int t = threadIdx.x;
  const float* qpRow = Pq + (size_t)(bz * NSQ + qy) * 512;

  // --- staging: X1 build (swizzled) + full variance head ---
  {
    const int m   = t >> 2;     // 0..63 pair row
    const int sub = t & 3;      // 0..3, 64 cols each
    const float* kpRow = Pk + (size_t)(bz * NSK + kt * 64 + m) * 512;
    const int msw = (m & 7);
    float vpart = 0.f;
    #pragma unroll
    for (int it = 0; it < 8; ++it) {
      const int c = sub * 64 + it * 8;      // 8 consecutive cols
      float4 q0 = *(const float4*)(qpRow + c);
      float4 q1 = *(const float4*)(qpRow + c + 4);
      float4 k0 = *(const float4*)(kpRow + c);
      float4 k1 = *(const float4*)(kpRow + c + 4);
      ushort2 p0 = f2bf2(relu_(q0.x + k0.x), relu_(q0.y + k0.y));
      ushort2 p1 = f2bf2(relu_(q0.z + k0.z), relu_(q0.w + k0.w));
      ushort2 p2 = f2bf2(relu_(q1.x + k1.x), relu_(q1.y + k1.y));
      ushort2 p3 = f2bf2(relu_(q1.z + k1.z), relu_(q1.w + k1.w));
      u16x8 hb;
      hb[0] = p0.x; hb[1] = p0.y; hb[2] = p1.x; hb[3] = p1.y;
      hb[4] = p2.x; hb[5] = p2.y; hb[6] = p3.x; hb[7] = p3.y;
      const int chunk = (sub * 8 + it) ^ msw;     // XOR swizzle
      *(u16x8*)&sXH[m * 256 + chunk * 8] = hb;
      // variance head partial
      float4 a0 = *(const float4*)(qpRow + 256 + c);
      float4 a1 = *(const float4*)(qpRow + 256 + c + 4);
      float4 v0 = *(const float4*)(kpRow + 256 + c);
      float4 v1 = *(const float4*)(kpRow + 256 + c + 4);
      float4 w0 = *(const float4*)(Wv2 + c);
      float4 w1 = *(const float4*)(Wv2 + c + 4);
      vpart += relu_(a0.x + v0.x) * w0.x + relu_(a0.y + v0.y) * w0.y
             + relu_(a0.z + v0.z) * w0.z + relu_(a0.w + v0.w) * w0.w
             + relu_(a1.x + v1.x) * w1.x + relu_(a1.y + v1.y) * w1.y
             + relu_(a1.z + v1.z) * w1.z + relu_(a1.w + v1.w) * w1.w;
    }
    // reduce over the 4 threads of this row (adjacent lanes) and store
    vpart += __shfl_xor(vpart, 1, 64);
    vpart += __shfl_xor(vpart, 2, 64);
    if (sub == 0) {
      const size_t o = (size_t)(bz * NSQ + qy) * NSK + kt * 64 + m;
      out[(size_t)NB * NSQ * NSK + o] = softplus_(vpart + bv2p[0]);
    }
    sB2[t] = b2[t]; sB3[t] = b3[t]; sWf[t] = Wf[t];
  }
  __syncthreads();

  const int wave = t >> 6, lane = t & 63;
  const int l15 = lane & 15, q4 = lane >> 4;
  const int lsw = l15 & 7;

  // --- GEMM1: D1[n][m] = sum_k W2[k][n] * X1[m][k] ---
  f32x4 acc[4][4];
  #pragma unroll
  for (int ft = 0; ft < 4; ++ft)
    #pragma unroll
    for (int pt = 0; pt < 4; ++pt)
      acc[ft][pt] = (f32x4){0.f, 0.f, 0.f, 0.f};

  #pragma unroll
  for (int s = 0; s < 8; ++s) {
    bf16x8 af[4], bfr[4];
    #pragma unroll
    for (int ft = 0; ft < 4; ++ft) {
      const int tg = wave * 4 + ft;
      af[ft] = *(const bf16x8*)(W2F + ((size_t)(tg * 8 + s) * 64 + lane) * 8);
    }
    #pragma unroll
    for (int pt = 0; pt < 4; ++pt) {
      const int chunk = ((s << 2) + q4) ^ lsw;
      bfr[pt] = *(const bf16x8*)&sXH[(pt * 16 + l15) * 256 + chunk * 8];
    }
    #pragma unroll
    for (int ft = 0; ft < 4; ++ft)
      #pragma unroll
      for (int pt = 0; pt < 4; ++pt)
        acc[ft][pt] = __builtin_amdgcn_mfma_f32_16x16x32_bf16(af[ft], bfr[pt], acc[ft][pt], 0, 0, 0);
  }
  __syncthreads();   // all X1 reads done before overwrite

  // --- Epilogue 1: H1 = relu(D1 + b2) -> bf16, same LDS buffer (swizzled) ---
  #pragma unroll
  for (int ft = 0; ft < 4; ++ft) {
    const int tg = wave * 4 + ft;
    const int n0 = tg * 16 + q4 * 4;
    float4 b4 = *(const float4*)&sB2[n0];
    const int chunkS = ((n0 >> 3) ^ lsw);
    #pragma unroll
    for (int pt = 0; pt < 4; ++pt) {
      const int mr = pt * 16 + l15;
      f32x4 a = acc[ft][pt];
      ushort2 lo = f2bf2(relu_(a[0] + b4.x), relu_(a[1] + b4.y));
      ushort2 hi = f2bf2(relu_(a[2] + b4.z), relu_(a[3] + b4.w));
      ushort4 h; h.x = lo.x; h.y = lo.y; h.z = hi.x; h.w = hi.y;
      *(ushort4*)&sXH[mr * 256 + chunkS * 8 + (n0 & 7)] = h;
    }
  }
  __syncthreads();

  // --- GEMM2: D2[n][m] = sum_k W3[k][n] * H1[m][k] ---
  f32x4 acc2[4][4];
  #pragma unroll
  for (int ft = 0; ft < 4; ++ft)
    #pragma unroll
    for (int pt = 0; pt < 4; ++pt)
      acc2[ft][pt] = (f32x4){0.f, 0.f, 0.f, 0.f};

  #pragma unroll
  for (int s = 0; s < 8; ++s) {
    bf16x8 af[4], bfr[4];
    #pragma unroll
    for (int ft = 0; ft < 4; ++ft) {
      const int tg = wave * 4 + ft;
      af[ft] = *(const bf16x8*)(W3F + ((size_t)(tg * 8 + s) * 64 + lane) * 8);
    }
    #pragma unroll
    for (int pt = 0; pt < 4; ++pt) {
      const int chunk = ((s << 2) + q4) ^ lsw;
      bfr[pt] = *(const bf16x8*)&sXH[(pt * 16 + l15) * 256 + chunk * 8];
    }
    #pragma unroll
    for (int ft = 0; ft < 4; ++ft)
      #pragma unroll
      for (int pt = 0; pt < 4; ++pt)
        acc2[ft][pt] = __builtin_amdgcn_mfma_f32_16x16x32_bf16(af[ft], bfr[pt], acc2[ft][pt], 0, 0, 0);
  }

  // --- Final epilogue: logit partials over this wave's 64 n-cols ---
  float p[4] = {0.f, 0.f, 0.f, 0.f};
  #pragma unroll
  for (int ft = 0; ft < 4; ++ft) {
    const int tg = wave * 4 + ft;
    const int n0 = tg * 16 + q4 * 4;
    float4 b4 = *(const float4*)&sB3[n0];
    float4 w4 = *(const float4*)&sWf[n0];
    #pragma unroll
    for (int pt = 0; pt < 4; ++pt) {
      f32x4 a = acc2[ft][pt];
      p[pt] += relu_(a[0] + b4.x) * w4.x + relu_(a[1] + b4.y) * w4.y
             + relu_(a[2] + b4.z) * w4.z + relu_(a[3] + b4.w) * w4.w;
    }
  }
  // sRed aliases sB2; all sB2 reads happened before the pre-GEMM2 barrier.
  #pragma unroll
  for (int pt = 0; pt < 4; ++pt) {
    float v = p[pt];
    v += __shfl_xor(v, 16, 64);
    v += __shfl_xor(v, 32, 64);
    if (lane < 16) sRed[wave * 64 + pt * 16 + lane] = v;
  }
  __syncthreads();

  if (t < 64) {
    const size_t o = (size_t)(bz * NSQ + qy) * NSK + kt * 64 + t;
    float lg = bfp[0] + sRed[t] + sRed[64 + t] + sRed[128 + t] + sRed[192 + t];
    out[o] = lg;
  }
}

// ---------------------------------------------------------------------------
extern "C" void kernel_launch(void* const* d_in, const int* in_sizes, int n_in,
                              void* d_out, int out_size, void* d_ws, size_t ws_size,
                              hipStream_t stream)
{
  (void)in_sizes; (void)n_in; (void)out_size; (void)ws_size;
  const float* query = (const float*)d_in[0];
  const float* key   = (const float*)d_in[1];
  const float* Wqe   = (const float*)d_in[2];
  const float* bqe   = (const float*)d_in[3];
  const float* Wke   = (const float*)d_in[4];
  const float* bke   = (const float*)d_in[5];
  const float* W1    = (const float*)d_in[6];
  const float* b1    = (const float*)d_in[7];
  const float* W2    = (const float*)d_in[8];
  const float* b2    = (const float*)d_in[9];
  const float* W3    = (const float*)d_in[10];
  const float* b3    = (const float*)d_in[11];
  const float* Wf    = (const float*)d_in[12];
  const float* bf    = (const float*)d_in[13];
  const float* Wv1   = (const float*)d_in[14];
  const float* bv1   = (const float*)d_in[15];
  const float* Wv2   = (const float*)d_in[16];
  const float* bv2   = (const float*)d_in[17];

  unsigned short* wsb = (unsigned short*)d_ws;
  float* Pq = (float*)((char*)d_ws + BF16_WS_END_BYTES);   // [1024][512]
  float* Pk = Pq + (size_t)1024 * 512;                     // [1024][512]
  float* out = (float*)d_out;

  shuffle_weights<<<1280, 64, 0, stream>>>(Wqe, Wke, W1, Wv1, W2, W3, wsb);
  encoder_kernel<<<64, 256, 0, stream>>>(query, key, bqe, bke, b1, bv1,
      wsb + OFF_WQEF, wsb + OFF_WKEF, wsb + OFF_WCQ, wsb + OFF_WCK, Pq, Pk);
  pair_kernel<<<dim3(NSK / 64, NSQ, NB), 256, 0, stream>>>(Pq, Pk,
      wsb + OFF_W2F, wsb + OFF_W3F, b2, b3, Wf, bf, Wv2, bv2, out);
}

// Round 4
// 281.249 us; speedup vs baseline: 1.6730x; 1.6730x over previous
//
#include <hip/hip_runtime.h>
#include <hip/hip_bf16.h>
#include <cstdint>
#include <cstddef>

// Problem constants
#define HDIM 256
#define EDIM 512
#define NB   2
#define NSQ  512
#define NSK  512

typedef __bf16 bf16x8 __attribute__((ext_vector_type(8)));
typedef float  f32x4  __attribute__((ext_vector_type(4)));
typedef unsigned short u16x8 __attribute__((ext_vector_type(8)));

// Workspace layout (in ushort elements for the bf16 region)
#define OFF_W2F  0u          // 16 tiles x 8 s x 64 x 8  = 65536
#define OFF_W3F  65536u
#define OFF_WQEF 131072u     // 16 tiles x 16 s x 64 x 8 = 131072
#define OFF_WKEF 262144u
#define OFF_WCQ  393216u     // 32 tiles x 8 s x 64 x 8  = 131072
#define OFF_WCK  524288u
#define BF16_WS_END_BYTES 1310720u   // 655360 ushorts * 2

// packed RNE f32x2 -> bf16x2 (v_cvt_pk_bf16_f32 on gfx950)
__device__ __forceinline__ ushort2 f2bf2(float x, float y) {
  __hip_bfloat162 h = __float22bfloat162_rn(float2{x, y});
  return *(ushort2*)&h;
}
__device__ __forceinline__ float relu_(float x) { return x > 0.f ? x : 0.f; }
__device__ __forceinline__ float softplus_(float x) {
  return fmaxf(x, 0.f) + log1pf(expf(-fabsf(x)));
}

// ---------------------------------------------------------------------------
// K1: shuffle fp32 weights into bf16 MFMA A-fragment order.
// A = W^T (A[n][k] = W[k][n]), layout [tile t][kstep s][lane][j=0..7]:
//   out[((t*S+s)*64+lane)*8 + j] = W[(s*32 + (lane>>4)*8 + j)*256 + t*16 + (lane&15)]
// ---------------------------------------------------------------------------
__global__ __launch_bounds__(64) void shuffle_weights(
    const float* __restrict__ Wqe, const float* __restrict__ Wke,
    const float* __restrict__ W1,  const float* __restrict__ Wv1,
    const float* __restrict__ W2,  const float* __restrict__ W3,
    unsigned short* __restrict__ wsb)
{
  const int bx = blockIdx.x;
  const int lane = threadIdx.x;
  const float* src; unsigned short* dst; int S; int idx;
  if      (bx <  128) { src = W2;          dst = wsb + OFF_W2F;           S = 8;  idx = bx;        }
  else if (bx <  256) { src = W3;          dst = wsb + OFF_W3F;           S = 8;  idx = bx - 128;  }
  else if (bx <  512) { src = Wqe;         dst = wsb + OFF_WQEF;          S = 16; idx = bx - 256;  }
  else if (bx <  768) { src = Wke;         dst = wsb + OFF_WKEF;          S = 16; idx = bx - 512;  }
  else if (bx <  896) { src = W1;          dst = wsb + OFF_WCQ;           S = 8;  idx = bx - 768;  }
  else if (bx < 1024) { src = Wv1;         dst = wsb + OFF_WCQ + 65536u;  S = 8;  idx = bx - 896;  }
  else if (bx < 1152) { src = W1 + 65536;  dst = wsb + OFF_WCK;           S = 8;  idx = bx - 1024; }
  else                { src = Wv1 + 65536; dst = wsb + OFF_WCK + 65536u;  S = 8;  idx = bx - 1152; }
  const int t = idx / S, s = idx % S;
  const int n  = t * 16 + (lane & 15);
  const int k0 = s * 32 + ((lane >> 4) << 3);
  unsigned short* o = dst + ((size_t)(t * S + s) * 64 + lane) * 8;
  #pragma unroll
  for (int j = 0; j < 8; j += 2) {
    ushort2 pp = f2bf2(src[(size_t)(k0 + j) * 256 + n], src[(size_t)(k0 + j + 1) * 256 + n]);
    *(ushort2*)&o[j] = pp;
  }
}

// ---------------------------------------------------------------------------
// K2: encoder + projections.
//  F  = relu(X @ We + be)               [rows, 256]
//  P  = F @ Wcat (+ b1|bv1 on q side)   [rows, 512]  (cols 0..255 = qp/kp, 256..511 = vq/vk)
// One block = 32 rows of one side. 64 blocks total.
// ---------------------------------------------------------------------------
__global__ __launch_bounds__(256) void encoder_kernel(
    const float* __restrict__ query, const float* __restrict__ key,
    const float* __restrict__ bqe,   const float* __restrict__ bke,
    const float* __restrict__ b1,    const float* __restrict__ bv1,
    const unsigned short* __restrict__ WqeF, const unsigned short* __restrict__ WkeF,
    const unsigned short* __restrict__ WcqF, const unsigned short* __restrict__ WckF,
    float* __restrict__ Pq, float* __restrict__ Pk)
{
  __shared__ unsigned short sX[32 * 520];   // X rows, bf16, pad +8
  __shared__ unsigned short sF[32 * 264];   // F rows, bf16, pad +8
  __shared__ float sBe[256];
  __shared__ float sBc[512];

  const int bx   = blockIdx.x;
  const int side = bx >> 5;          // 0 = q, 1 = k
  const int rt   = bx & 31;
  const int t    = threadIdx.x;

  const float* Xsrc = side ? key : query;
  const unsigned short* WeF = side ? WkeF : WqeF;
  const unsigned short* WcF = side ? WckF : WcqF;
  float* P = side ? Pk : Pq;

  {
    const int m = t >> 3, ch = t & 7;
    const int c0 = ch * 64;
    const float* xr = Xsrc + (size_t)(rt * 32 + m) * EDIM;
    #pragma unroll
    for (int cc = 0; cc < 64; cc += 4) {
      const int c = c0 + cc;
      float4 xv = *(const float4*)(xr + c);
      ushort2 lo = f2bf2(xv.x, xv.y);
      ushort2 hi = f2bf2(xv.z, xv.w);
      ushort4 xb; xb.x = lo.x; xb.y = lo.y; xb.z = hi.x; xb.w = hi.y;
      *(ushort4*)&sX[m * 520 + c] = xb;
    }
    sBe[t]       = side ? bke[t] : bqe[t];
    sBc[t]       = side ? 0.f : b1[t];
    sBc[256 + t] = side ? 0.f : bv1[t];
  }
  __syncthreads();

  const int wave = t >> 6, lane = t & 63;
  const int l15 = lane & 15, q4 = lane >> 4;

  // GEMM1e: D[n][m] = sum_k We[k][n] * X[m][k], K = 512 (16 k-steps)
  f32x4 acc1[4][2];
  #pragma unroll
  for (int ft = 0; ft < 4; ++ft)
    #pragma unroll
    for (int pt = 0; pt < 2; ++pt)
      acc1[ft][pt] = (f32x4){0.f, 0.f, 0.f, 0.f};

  for (int s = 0; s < 16; ++s) {
    bf16x8 af[4], bfr[2];
    #pragma unroll
    for (int ft = 0; ft < 4; ++ft) {
      const int tg = wave * 4 + ft;
      af[ft] = *(const bf16x8*)(WeF + ((size_t)(tg * 16 + s) * 64 + lane) * 8);
    }
    #pragma unroll
    for (int pt = 0; pt < 2; ++pt)
      bfr[pt] = *(const bf16x8*)&sX[(pt * 16 + l15) * 520 + s * 32 + q4 * 8];
    #pragma unroll
    for (int ft = 0; ft < 4; ++ft)
      #pragma unroll
      for (int pt = 0; pt < 2; ++pt)
        acc1[ft][pt] = __builtin_amdgcn_mfma_f32_16x16x32_bf16(af[ft], bfr[pt], acc1[ft][pt], 0, 0, 0);
  }

  // Epilogue 1: F = relu(D + be) -> bf16 LDS [m][n]
  #pragma unroll
  for (int ft = 0; ft < 4; ++ft) {
    const int tg = wave * 4 + ft;
    const int n0 = tg * 16 + q4 * 4;
    float4 b4 = *(const float4*)&sBe[n0];
    #pragma unroll
    for (int pt = 0; pt < 2; ++pt) {
      const int mr = pt * 16 + l15;
      f32x4 a = acc1[ft][pt];
      ushort2 lo = f2bf2(relu_(a[0] + b4.x), relu_(a[1] + b4.y));
      ushort2 hi = f2bf2(relu_(a[2] + b4.z), relu_(a[3] + b4.w));
      ushort4 h; h.x = lo.x; h.y = lo.y; h.z = hi.x; h.w = hi.y;
      *(ushort4*)&sF[mr * 264 + n0] = h;
    }
  }
  __syncthreads();

  // GEMM2e: P[n][m] = sum_k Wcat[k][n] * F[m][k], nout = 512 (32 tiles), K = 256 (8 steps)
  f32x4 acc2[8][2];
  #pragma unroll
  for (int ft = 0; ft < 8; ++ft)
    #pragma unroll
    for (int pt = 0; pt < 2; ++pt)
      acc2[ft][pt] = (f32x4){0.f, 0.f, 0.f, 0.f};

  for (int s = 0; s < 8; ++s) {
    bf16x8 af[8], bfr[2];
    #pragma unroll
    for (int ft = 0; ft < 8; ++ft) {
      const int tg = wave * 8 + ft;
      af[ft] = *(const bf16x8*)(WcF + ((size_t)(tg * 8 + s) * 64 + lane) * 8);
    }
    #pragma unroll
    for (int pt = 0; pt < 2; ++pt)
      bfr[pt] = *(const bf16x8*)&sF[(pt * 16 + l15) * 264 + s * 32 + q4 * 8];
    #pragma unroll
    for (int ft = 0; ft < 8; ++ft)
      #pragma unroll
      for (int pt = 0; pt < 2; ++pt)
        acc2[ft][pt] = __builtin_amdgcn_mfma_f32_16x16x32_bf16(af[ft], bfr[pt], acc2[ft][pt], 0, 0, 0);
  }

  // Epilogue 2: store P[row][n] = D + bias (fp32, no relu)
  #pragma unroll
  for (int ft = 0; ft < 8; ++ft) {
    const int tg = wave * 8 + ft;
    const int n0 = tg * 16 + q4 * 4;
    float4 bc = *(const float4*)&sBc[n0];
    #pragma unroll
    for (int pt = 0; pt < 2; ++pt) {
      const int mr = pt * 16 + l15;
      const int row = rt * 32 + mr;
      f32x4 a = acc2[ft][pt];
      float4 o;
      o.x = a[0] + bc.x; o.y = a[1] + bc.y; o.z = a[2] + bc.z; o.w = a[3] + bc.w;
      *(float4*)&P[(size_t)row * 512 + n0] = o;
    }
  }
}

// ---------------------------------------------------------------------------
// K3: fused pair kernel. One block = (b, q, 64 consecutive k). 512 threads.
// 8 waves; wave w owns n-tiles {2w, 2w+1} (32 n-cols), all 64 m (acc 2x4).
// LDS XOR swizzle: 16B chunk c of row m stored at chunk c ^ (m&7).
//   X1 = relu(qp' + kp)            (LDS bf16, swizzled [64][256])
//   H1 = relu(X1 @ W2 + b2)        (MFMA transposed-out, same LDS)
//   H2 = relu(H1 @ W3 + b3)        (MFMA)
//   logit = H2 . Wf + bf
//   var   = softplus(relu(vq'+vk) . Wv2 + bv2)  (VALU during staging,
//           shfl-reduced over the 8 threads/row, stored directly)
// A-fragment loads are double-buffered across the k-step loop (s+1 in
// flight while s computes); budget 128 regs via launch_bounds(512,4) —
// NOTE: (256,4)/(512,6) style tight bounds spill the AGPR acc (R3: +59MB
// scratch writes). VGPR+AGPR must fit the bound together.
// ---------------------------------------------------------------------------
__global__ __launch_bounds__(512, 4) void pair_kernel(
    const float* __restrict__ Pq, const float* __restrict__ Pk,
    const unsigned short* __restrict__ W2F, const unsigned short* __restrict__ W3F,
    const float* __restrict__ b2, const float* __restrict__ b3,
    const float* __restrict__ Wf, const float* __restrict__ bfp,
    const float* __restrict__ Wv2, const float* __restrict__ bv2p,
    float* __restrict__ out)
{
  // Manual LDS carving; sRed aliases sB2+sB3 (dead after the final-epilogue
  // reads, ordered by the barrier before sRed writes).
  __shared__ __align__(16) unsigned char smem[35840];
  unsigned short* sXH = (unsigned short*)smem;        // 64*256 bf16 = 32768 B
  float* sB2   = (float*)(smem + 32768);              // 1024 B
  float* sB3   = (float*)(smem + 33792);              // 1024 B
  float* sWf   = (float*)(smem + 34816);              // 1024 B
  float* sRed  = (float*)(smem + 32768);              // 8*64*4 = 2048 B (alias)

  const int kt = blockIdx.x, qy = blockIdx.y, bz = blockIdx.z;
  const int t = threadIdx.x;
  const float* qpRow = Pq + (size_t)(bz * NSQ + qy) * 512;

  const int wave = t >> 6, lane = t & 63;
  const int l15 = lane & 15, q4 = lane >> 4;
  const int lsw = l15 & 7;

  // Per-wave A-fragment base pointers (n-tiles 2w, 2w+1), s-stride 512 ushorts.
  const unsigned short* a2base = W2F + ((size_t)(wave * 2) * 8 * 64 + lane) * 8;
  const unsigned short* a3base = W3F + ((size_t)(wave * 2) * 8 * 64 + lane) * 8;

  // Issue s=0 A-loads for GEMM1 before staging (independent of staging).
  bf16x8 afd[2][2];
  afd[0][0] = *(const bf16x8*)(a2base);
  afd[0][1] = *(const bf16x8*)(a2base + 8 * 64 * 8);

  // --- staging: X1 build (swizzled) + full variance head ---
  {
    const int m   = t >> 3;     // 0..63 pair row
    const int sub = t & 7;      // 0..7
    const float* kpRow = Pk + (size_t)(bz * NSK + kt * 64 + m) * 512;
    const int msw = (m & 7);
    float vpart = 0.f;
    #pragma unroll
    for (int it = 0; it < 4; ++it) {
      const int c = it * 64 + sub * 8;      // 8 consecutive cols
      float4 q0 = *(const float4*)(qpRow + c);
      float4 q1 = *(const float4*)(qpRow + c + 4);
      float4 k0 = *(const float4*)(kpRow + c);
      float4 k1 = *(const float4*)(kpRow + c + 4);
      ushort2 p0 = f2bf2(relu_(q0.x + k0.x), relu_(q0.y + k0.y));
      ushort2 p1 = f2bf2(relu_(q0.z + k0.z), relu_(q0.w + k0.w));
      ushort2 p2 = f2bf2(relu_(q1.x + k1.x), relu_(q1.y + k1.y));
      ushort2 p3 = f2bf2(relu_(q1.z + k1.z), relu_(q1.w + k1.w));
      u16x8 hb;
      hb[0] = p0.x; hb[1] = p0.y; hb[2] = p1.x; hb[3] = p1.y;
      hb[4] = p2.x; hb[5] = p2.y; hb[6] = p3.x; hb[7] = p3.y;
      const int chunk = (c >> 3) ^ msw;     // XOR swizzle
      *(u16x8*)&sXH[m * 256 + chunk * 8] = hb;
      // variance head partial
      float4 a0 = *(const float4*)(qpRow + 256 + c);
      float4 a1 = *(const float4*)(qpRow + 256 + c + 4);
      float4 v0 = *(const float4*)(kpRow + 256 + c);
      float4 v1 = *(const float4*)(kpRow + 256 + c + 4);
      float4 w0 = *(const float4*)(Wv2 + c);
      float4 w1 = *(const float4*)(Wv2 + c + 4);
      vpart += relu_(a0.x + v0.x) * w0.x + relu_(a0.y + v0.y) * w0.y
             + relu_(a0.z + v0.z) * w0.z + relu_(a0.w + v0.w) * w0.w
             + relu_(a1.x + v1.x) * w1.x + relu_(a1.y + v1.y) * w1.y
             + relu_(a1.z + v1.z) * w1.z + relu_(a1.w + v1.w) * w1.w;
    }
    // reduce over the 8 threads of this row (adjacent lanes) and store
    vpart += __shfl_xor(vpart, 1, 64);
    vpart += __shfl_xor(vpart, 2, 64);
    vpart += __shfl_xor(vpart, 4, 64);
    if (sub == 0) {
      const size_t o = (size_t)(bz * NSQ + qy) * NSK + kt * 64 + m;
      out[(size_t)NB * NSQ * NSK + o] = softplus_(vpart + bv2p[0]);
    }
    if (t < 256) { sB2[t] = b2[t]; sB3[t] = b3[t]; sWf[t] = Wf[t]; }
  }
  __syncthreads();

  // --- GEMM1: D1[n][m] = sum_k W2[k][n] * X1[m][k], A double-buffered ---
  f32x4 acc[2][4];
  #pragma unroll
  for (int ft = 0; ft < 2; ++ft)
    #pragma unroll
    for (int pt = 0; pt < 4; ++pt)
      acc[ft][pt] = (f32x4){0.f, 0.f, 0.f, 0.f};

  #pragma unroll
  for (int s = 0; s < 8; ++s) {
    if (s < 7) {
      afd[(s + 1) & 1][0] = *(const bf16x8*)(a2base + (size_t)(s + 1) * 512);
      afd[(s + 1) & 1][1] = *(const bf16x8*)(a2base + 8 * 64 * 8 + (size_t)(s + 1) * 512);
    }
    bf16x8 bfr[4];
    #pragma unroll
    for (int pt = 0; pt < 4; ++pt) {
      const int chunk = ((s << 2) + q4) ^ lsw;
      bfr[pt] = *(const bf16x8*)&sXH[(pt * 16 + l15) * 256 + chunk * 8];
    }
    #pragma unroll
    for (int ft = 0; ft < 2; ++ft)
      #pragma unroll
      for (int pt = 0; pt < 4; ++pt)
        acc[ft][pt] = __builtin_amdgcn_mfma_f32_16x16x32_bf16(afd[s & 1][ft], bfr[pt], acc[ft][pt], 0, 0, 0);
  }
  __syncthreads();   // all X1 reads done before overwrite

  // Prefetch GEMM2 s=0 A-frags during epilogue 1.
  afd[0][0] = *(const bf16x8*)(a3base);
  afd[0][1] = *(const bf16x8*)(a3base + 8 * 64 * 8);

  // --- Epilogue 1: H1 = relu(D1 + b2) -> bf16, same LDS buffer (swizzled) ---
  #pragma unroll
  for (int ft = 0; ft < 2; ++ft) {
    const int tg = wave * 2 + ft;
    const int n0 = tg * 16 + q4 * 4;
    float4 b4 = *(const float4*)&sB2[n0];
    const int chunkS = ((n0 >> 3) ^ lsw);
    #pragma unroll
    for (int pt = 0; pt < 4; ++pt) {
      const int mr = pt * 16 + l15;
      f32x4 a = acc[ft][pt];
      ushort2 lo = f2bf2(relu_(a[0] + b4.x), relu_(a[1] + b4.y));
      ushort2 hi = f2bf2(relu_(a[2] + b4.z), relu_(a[3] + b4.w));
      ushort4 h; h.x = lo.x; h.y = lo.y; h.z = hi.x; h.w = hi.y;
      *(ushort4*)&sXH[mr * 256 + chunkS * 8 + (n0 & 7)] = h;
    }
  }
  __syncthreads();

  // --- GEMM2: D2[n][m] = sum_k W3[k][n] * H1[m][k], A double-buffered ---
  f32x4 acc2[2][4];
  #pragma unroll
  for (int ft = 0; ft < 2; ++ft)
    #pragma unroll
    for (int pt = 0; pt < 4; ++pt)
      acc2[ft][pt] = (f32x4){0.f, 0.f, 0.f, 0.f};

  #pragma unroll
  for (int s = 0; s < 8; ++s) {
    if (s < 7) {
      afd[(s + 1) & 1][0] = *(const bf16x8*)(a3base + (size_t)(s + 1) * 512);
      afd[(s + 1) & 1][1] = *(const bf16x8*)(a3base + 8 * 64 * 8 + (size_t)(s + 1) * 512);
    }
    bf16x8 bfr[4];
    #pragma unroll
    for (int pt = 0; pt < 4; ++pt) {
      const int chunk = ((s << 2) + q4) ^ lsw;
      bfr[pt] = *(const bf16x8*)&sXH[(pt * 16 + l15) * 256 + chunk * 8];
    }
    #pragma unroll
    for (int ft = 0; ft < 2; ++ft)
      #pragma unroll
      for (int pt = 0; pt < 4; ++pt)
        acc2[ft][pt] = __builtin_amdgcn_mfma_f32_16x16x32_bf16(afd[s & 1][ft], bfr[pt], acc2[ft][pt], 0, 0, 0);
  }

  // --- Final epilogue: logit partials over this wave's 32 n-cols ---
  float p[4] = {0.f, 0.f, 0.f, 0.f};
  #pragma unroll
  for (int ft = 0; ft < 2; ++ft) {
    const int tg = wave * 2 + ft;
    const int n0 = tg * 16 + q4 * 4;
    float4 b4 = *(const float4*)&sB3[n0];
    float4 w4 = *(const float4*)&sWf[n0];
    #pragma unroll
    for (int pt = 0; pt < 4; ++pt) {
      f32x4 a = acc2[ft][pt];
      p[pt] += relu_(a[0] + b4.x) * w4.x + relu_(a[1] + b4.y) * w4.y
             + relu_(a[2] + b4.z) * w4.z + relu_(a[3] + b4.w) * w4.w;
    }
  }
  __syncthreads();   // sB2/sB3 reads done before sRed (alias) writes
  #pragma unroll
  for (int pt = 0; pt < 4; ++pt) {
    float v = p[pt];
    v += __shfl_xor(v, 16, 64);
    v += __shfl_xor(v, 32, 64);
    if (lane < 16) sRed[wave * 64 + pt * 16 + lane] = v;
  }
  __syncthreads();

  if (t < 64) {
    const size_t o = (size_t)(bz * NSQ + qy) * NSK + kt * 64 + t;
    float lg = bfp[0];
    #pragma unroll
    for (int w = 0; w < 8; ++w) lg += sRed[w * 64 + t];
    out[o] = lg;
  }
}

// ---------------------------------------------------------------------------
extern "C" void kernel_launch(void* const* d_in, const int* in_sizes, int n_in,
                              void* d_out, int out_size, void* d_ws, size_t ws_size,
                              hipStream_t stream)
{
  (void)in_sizes; (void)n_in; (void)out_size; (void)ws_size;
  const float* query = (const float*)d_in[0];
  const float* key   = (const float*)d_in[1];
  const float* Wqe   = (const float*)d_in[2];
  const float* bqe   = (const float*)d_in[3];
  const float* Wke   = (const float*)d_in[4];
  const float* bke   = (const float*)d_in[5];
  const float* W1    = (const float*)d_in[6];
  const float* b1    = (const float*)d_in[7];
  const float* W2    = (const float*)d_in[8];
  const float* b2    = (const float*)d_in[9];
  const float* W3    = (const float*)d_in[10];
  const float* b3    = (const float*)d_in[11];
  const float* Wf    = (const float*)d_in[12];
  const float* bf    = (const float*)d_in[13];
  const float* Wv1   = (const float*)d_in[14];
  const float* bv1   = (const float*)d_in[15];
  const float* Wv2   = (const float*)d_in[16];
  const float* bv2   = (const float*)d_in[17];

  unsigned short* wsb = (unsigned short*)d_ws;
  float* Pq = (float*)((char*)d_ws + BF16_WS_END_BYTES);   // [1024][512]
  float* Pk = Pq + (size_t)1024 * 512;                     // [1024][512]
  float* out = (float*)d_out;

  shuffle_weights<<<1280, 64, 0, stream>>>(Wqe, Wke, W1, Wv1, W2, W3, wsb);
  encoder_kernel<<<64, 256, 0, stream>>>(query, key, bqe, bke, b1, bv1,
      wsb + OFF_WQEF, wsb + OFF_WKEF, wsb + OFF_WCQ, wsb + OFF_WCK, Pq, Pk);
  pair_kernel<<<dim3(NSK / 64, NSQ, NB), 512, 0, stream>>>(Pq, Pk,
      wsb + OFF_W2F, wsb + OFF_W3F, b2, b3, Wf, bf, Wv2, bv2, out);
}

// Round 6
// 265.272 us; speedup vs baseline: 1.7737x; 1.0602x over previous
//
#include <hip/hip_runtime.h>
#include <hip/hip_bf16.h>
#include <cstdint>
#include <cstddef>
#include <cstring>

// Problem constants
#define HDIM 256
#define EDIM 512
#define NB   2
#define NSQ  512
#define NSK  512

typedef _Float16 f16x8 __attribute__((ext_vector_type(8)));
typedef _Float16 h2    __attribute__((ext_vector_type(2)));
typedef __fp16   fp16v2 __attribute__((ext_vector_type(2)));
typedef float    f32x4 __attribute__((ext_vector_type(4)));
typedef unsigned short u16x8 __attribute__((ext_vector_type(8)));

// Workspace layout (in ushort elements for the f16 region)
#define OFF_W2F  0u          // 16 tiles x 8 s x 64 x 8  = 65536
#define OFF_W3F  65536u
#define OFF_WQEF 131072u     // 16 tiles x 16 s x 64 x 8 = 131072
#define OFF_WKEF 262144u
#define OFF_WCQ  393216u     // 32 tiles x 8 s x 64 x 8  = 131072
#define OFF_WCK  524288u
#define OFF_WV2H 655360u     // 256 f16
#define F16_WS_END_BYTES 1312768u

union U8 { f16x8 v; h2 h[4]; };

// packed RTZ f32x2 -> f16x2 (v_cvt_pkrtz_f16_f32); bit-cast the __fp16x2 return
__device__ __forceinline__ ushort2 f2h2(float x, float y) {
  fp16v2 r = __builtin_amdgcn_cvt_pkrtz(x, y);
  ushort2 u;
  __builtin_memcpy(&u, &r, 4);
  return u;
}
__device__ __forceinline__ float relu_(float x) { return x > 0.f ? x : 0.f; }
__device__ __forceinline__ float softplus_(float x) {
  return fmaxf(x, 0.f) + log1pf(expf(-fabsf(x)));
}

// ---------------------------------------------------------------------------
// K1: shuffle fp32 weights into f16 MFMA A-fragment order.
// A = W^T (A[n][k] = W[k][n]), layout [tile t][kstep s][lane][j=0..7]:
//   out[((t*S+s)*64+lane)*8 + j] = W[(s*32 + (lane>>4)*8 + j)*256 + t*16 + (lane&15)]
// Block 1280: convert Wv2 (256 fp32) -> f16 table.
// ---------------------------------------------------------------------------
__global__ __launch_bounds__(64) void shuffle_weights(
    const float* __restrict__ Wqe, const float* __restrict__ Wke,
    const float* __restrict__ W1,  const float* __restrict__ Wv1,
    const float* __restrict__ W2,  const float* __restrict__ W3,
    const float* __restrict__ Wv2,
    unsigned short* __restrict__ wsb)
{
  const int bx = blockIdx.x;
  const int lane = threadIdx.x;
  if (bx == 1280) {
    float a = Wv2[lane * 4 + 0], b = Wv2[lane * 4 + 1];
    float c = Wv2[lane * 4 + 2], d = Wv2[lane * 4 + 3];
    ushort2 lo = f2h2(a, b), hi = f2h2(c, d);
    ushort4 o; o.x = lo.x; o.y = lo.y; o.z = hi.x; o.w = hi.y;
    *(ushort4*)&wsb[OFF_WV2H + lane * 4] = o;
    return;
  }
  const float* src; unsigned short* dst; int S; int idx;
  if      (bx <  128) { src = W2;          dst = wsb + OFF_W2F;           S = 8;  idx = bx;        }
  else if (bx <  256) { src = W3;          dst = wsb + OFF_W3F;           S = 8;  idx = bx - 128;  }
  else if (bx <  512) { src = Wqe;         dst = wsb + OFF_WQEF;          S = 16; idx = bx - 256;  }
  else if (bx <  768) { src = Wke;         dst = wsb + OFF_WKEF;          S = 16; idx = bx - 512;  }
  else if (bx <  896) { src = W1;          dst = wsb + OFF_WCQ;           S = 8;  idx = bx - 768;  }
  else if (bx < 1024) { src = Wv1;         dst = wsb + OFF_WCQ + 65536u;  S = 8;  idx = bx - 896;  }
  else if (bx < 1152) { src = W1 + 65536;  dst = wsb + OFF_WCK;           S = 8;  idx = bx - 1024; }
  else                { src = Wv1 + 65536; dst = wsb + OFF_WCK + 65536u;  S = 8;  idx = bx - 1152; }
  const int t = idx / S, s = idx % S;
  const int n  = t * 16 + (lane & 15);
  const int k0 = s * 32 + ((lane >> 4) << 3);
  unsigned short* o = dst + ((size_t)(t * S + s) * 64 + lane) * 8;
  #pragma unroll
  for (int j = 0; j < 8; j += 2) {
    ushort2 pp = f2h2(src[(size_t)(k0 + j) * 256 + n], src[(size_t)(k0 + j + 1) * 256 + n]);
    *(ushort2*)&o[j] = pp;
  }
}

// ---------------------------------------------------------------------------
// K2: encoder + projections (f16 fragments, f16 P output).
//  F  = relu(X @ We + be)               [rows, 256]
//  P  = F @ Wcat (+ b1|bv1 on q side)   [rows, 512] f16  (0..255 = qp/kp, 256..511 = vq/vk)
// One block = 32 rows of one side. 64 blocks total.
// ---------------------------------------------------------------------------
__global__ __launch_bounds__(256) void encoder_kernel(
    const float* __restrict__ query, const float* __restrict__ key,
    const float* __restrict__ bqe,   const float* __restrict__ bke,
    const float* __restrict__ b1,    const float* __restrict__ bv1,
    const unsigned short* __restrict__ WqeF, const unsigned short* __restrict__ WkeF,
    const unsigned short* __restrict__ WcqF, const unsigned short* __restrict__ WckF,
    _Float16* __restrict__ Pq, _Float16* __restrict__ Pk)
{
  __shared__ unsigned short sX[32 * 520];   // X rows, f16, pad +8
  __shared__ unsigned short sF[32 * 264];   // F rows, f16, pad +8
  __shared__ float sBe[256];
  __shared__ float sBc[512];

  const int bx   = blockIdx.x;
  const int side = bx >> 5;          // 0 = q, 1 = k
  const int rt   = bx & 31;
  const int t    = threadIdx.x;

  const float* Xsrc = side ? key : query;
  const unsigned short* WeF = side ? WkeF : WqeF;
  const unsigned short* WcF = side ? WckF : WcqF;
  _Float16* P = side ? Pk : Pq;

  {
    const int m = t >> 3, ch = t & 7;
    const int c0 = ch * 64;
    const float* xr = Xsrc + (size_t)(rt * 32 + m) * EDIM;
    #pragma unroll
    for (int cc = 0; cc < 64; cc += 4) {
      const int c = c0 + cc;
      float4 xv = *(const float4*)(xr + c);
      ushort2 lo = f2h2(xv.x, xv.y);
      ushort2 hi = f2h2(xv.z, xv.w);
      ushort4 xb; xb.x = lo.x; xb.y = lo.y; xb.z = hi.x; xb.w = hi.y;
      *(ushort4*)&sX[m * 520 + c] = xb;
    }
    sBe[t]       = side ? bke[t] : bqe[t];
    sBc[t]       = side ? 0.f : b1[t];
    sBc[256 + t] = side ? 0.f : bv1[t];
  }
  __syncthreads();

  const int wave = t >> 6, lane = t & 63;
  const int l15 = lane & 15, q4 = lane >> 4;

  // GEMM1e: D[n][m] = sum_k We[k][n] * X[m][k], K = 512 (16 k-steps)
  f32x4 acc1[4][2];
  #pragma unroll
  for (int ft = 0; ft < 4; ++ft)
    #pragma unroll
    for (int pt = 0; pt < 2; ++pt)
      acc1[ft][pt] = (f32x4){0.f, 0.f, 0.f, 0.f};

  for (int s = 0; s < 16; ++s) {
    f16x8 af[4], bfr[2];
    #pragma unroll
    for (int ft = 0; ft < 4; ++ft) {
      const int tg = wave * 4 + ft;
      af[ft] = *(const f16x8*)(WeF + ((size_t)(tg * 16 + s) * 64 + lane) * 8);
    }
    #pragma unroll
    for (int pt = 0; pt < 2; ++pt)
      bfr[pt] = *(const f16x8*)&sX[(pt * 16 + l15) * 520 + s * 32 + q4 * 8];
    #pragma unroll
    for (int ft = 0; ft < 4; ++ft)
      #pragma unroll
      for (int pt = 0; pt < 2; ++pt)
        acc1[ft][pt] = __builtin_amdgcn_mfma_f32_16x16x32_f16(af[ft], bfr[pt], acc1[ft][pt], 0, 0, 0);
  }

  // Epilogue 1: F = relu(D + be) -> f16 LDS [m][n]
  #pragma unroll
  for (int ft = 0; ft < 4; ++ft) {
    const int tg = wave * 4 + ft;
    const int n0 = tg * 16 + q4 * 4;
    float4 b4 = *(const float4*)&sBe[n0];
    #pragma unroll
    for (int pt = 0; pt < 2; ++pt) {
      const int mr = pt * 16 + l15;
      f32x4 a = acc1[ft][pt];
      ushort2 lo = f2h2(relu_(a[0] + b4.x), relu_(a[1] + b4.y));
      ushort2 hi = f2h2(relu_(a[2] + b4.z), relu_(a[3] + b4.w));
      ushort4 h; h.x = lo.x; h.y = lo.y; h.z = hi.x; h.w = hi.y;
      *(ushort4*)&sF[mr * 264 + n0] = h;
    }
  }
  __syncthreads();

  // GEMM2e: P[n][m] = sum_k Wcat[k][n] * F[m][k], nout = 512 (32 tiles), K = 256 (8 steps)
  f32x4 acc2[8][2];
  #pragma unroll
  for (int ft = 0; ft < 8; ++ft)
    #pragma unroll
    for (int pt = 0; pt < 2; ++pt)
      acc2[ft][pt] = (f32x4){0.f, 0.f, 0.f, 0.f};

  for (int s = 0; s < 8; ++s) {
    f16x8 af[8], bfr[2];
    #pragma unroll
    for (int ft = 0; ft < 8; ++ft) {
      const int tg = wave * 8 + ft;
      af[ft] = *(const f16x8*)(WcF + ((size_t)(tg * 8 + s) * 64 + lane) * 8);
    }
    #pragma unroll
    for (int pt = 0; pt < 2; ++pt)
      bfr[pt] = *(const f16x8*)&sF[(pt * 16 + l15) * 264 + s * 32 + q4 * 8];
    #pragma unroll
    for (int ft = 0; ft < 8; ++ft)
      #pragma unroll
      for (int pt = 0; pt < 2; ++pt)
        acc2[ft][pt] = __builtin_amdgcn_mfma_f32_16x16x32_f16(af[ft], bfr[pt], acc2[ft][pt], 0, 0, 0);
  }

  // Epilogue 2: store P[row][n] = f16(D + bias)
  #pragma unroll
  for (int ft = 0; ft < 8; ++ft) {
    const int tg = wave * 8 + ft;
    const int n0 = tg * 16 + q4 * 4;
    float4 bc = *(const float4*)&sBc[n0];
    #pragma unroll
    for (int pt = 0; pt < 2; ++pt) {
      const int mr = pt * 16 + l15;
      const int row = rt * 32 + mr;
      f32x4 a = acc2[ft][pt];
      ushort2 lo = f2h2(a[0] + bc.x, a[1] + bc.y);
      ushort2 hi = f2h2(a[2] + bc.z, a[3] + bc.w);
      ushort4 o; o.x = lo.x; o.y = lo.y; o.z = hi.x; o.w = hi.y;
      *(ushort4*)((unsigned short*)P + (size_t)row * 512 + n0) = o;
    }
  }
}

// ---------------------------------------------------------------------------
// K3: fused pair kernel. One block = (b, q, 64 consecutive k). 512 threads.
// 8 waves; wave w owns n-tiles {2w, 2w+1} (32 n-cols), all 64 m (acc 2x4).
// P is f16: staging is packed-f16 (v_pk_add/v_pk_max, v_dot2_f32_f16), no cvt.
// LDS XOR swizzle: 16B chunk c of row m stored at chunk c ^ (m&7).
// A-fragment loads double-buffered. launch_bounds(512,4): 128-reg budget —
// tighter bounds spill the AGPR acc (R3: +59MB scratch).
// ---------------------------------------------------------------------------
__global__ __launch_bounds__(512, 4) void pair_kernel(
    const _Float16* __restrict__ Pq, const _Float16* __restrict__ Pk,
    const unsigned short* __restrict__ W2F, const unsigned short* __restrict__ W3F,
    const float* __restrict__ b2, const float* __restrict__ b3,
    const float* __restrict__ Wf, const float* __restrict__ bfp,
    const unsigned short* __restrict__ Wv2H, const float* __restrict__ bv2p,
    float* __restrict__ out)
{
  __shared__ __align__(16) unsigned char smem[35840];
  unsigned short* sXH = (unsigned short*)smem;        // 64*256 f16 = 32768 B
  float* sB2   = (float*)(smem + 32768);              // 1024 B
  float* sB3   = (float*)(smem + 33792);              // 1024 B
  float* sWf   = (float*)(smem + 34816);              // 1024 B
  float* sRed  = (float*)(smem + 32768);              // 8*64*4 = 2048 B (alias)

  const int kt = blockIdx.x, qy = blockIdx.y, bz = blockIdx.z;
  const int t = threadIdx.x;
  const _Float16* qpRow = Pq + (size_t)(bz * NSQ + qy) * 512;

  const int wave = t >> 6, lane = t & 63;
  const int l15 = lane & 15, q4 = lane >> 4;
  const int lsw = l15 & 7;

  // Per-wave A-fragment base pointers (n-tiles 2w, 2w+1), s-stride 512 ushorts.
  const unsigned short* a2base = W2F + ((size_t)(wave * 2) * 8 * 64 + lane) * 8;
  const unsigned short* a3base = W3F + ((size_t)(wave * 2) * 8 * 64 + lane) * 8;

  // Issue s=0 A-loads for GEMM1 before staging.
  f16x8 afd[2][2];
  afd[0][0] = *(const f16x8*)(a2base);
  afd[0][1] = *(const f16x8*)(a2base + 8 * 64 * 8);

  // --- staging: X1 build (packed f16, swizzled) + variance head ---
  {
    const int m   = t >> 3;     // 0..63 pair row
    const int sub = t & 7;      // 0..7
    const _Float16* kpRow = Pk + (size_t)(bz * NSK + kt * 64 + m) * 512;
    const int msw = (m & 7);
    const f16x8 z8 = {0, 0, 0, 0, 0, 0, 0, 0};
    float vpart = 0.f;
    #pragma unroll
    for (int it = 0; it < 4; ++it) {
      const int c = it * 64 + sub * 8;      // 8 consecutive cols
      f16x8 q8 = *(const f16x8*)(qpRow + c);
      f16x8 k8 = *(const f16x8*)(kpRow + c);
      f16x8 r  = __builtin_elementwise_max(q8 + k8, z8);   // v_pk_add + v_pk_max
      const int chunk = (c >> 3) ^ msw;                    // XOR swizzle
      *(f16x8*)&sXH[m * 256 + chunk * 8] = r;
      // variance head: relu(vq+vk) . Wv2 via v_dot2_f32_f16
      f16x8 a8 = *(const f16x8*)(qpRow + 256 + c);
      f16x8 v8 = *(const f16x8*)(kpRow + 256 + c);
      U8 ar; ar.v = __builtin_elementwise_max(a8 + v8, z8);
      U8 w8; w8.v = *(const f16x8*)((const _Float16*)Wv2H + c);
      vpart = __builtin_amdgcn_fdot2(ar.h[0], w8.h[0], vpart, false);
      vpart = __builtin_amdgcn_fdot2(ar.h[1], w8.h[1], vpart, false);
      vpart = __builtin_amdgcn_fdot2(ar.h[2], w8.h[2], vpart, false);
      vpart = __builtin_amdgcn_fdot2(ar.h[3], w8.h[3], vpart, false);
    }
    // reduce over the 8 threads of this row (adjacent lanes) and store
    vpart += __shfl_xor(vpart, 1, 64);
    vpart += __shfl_xor(vpart, 2, 64);
    vpart += __shfl_xor(vpart, 4, 64);
    if (sub == 0) {
      const size_t o = (size_t)(bz * NSQ + qy) * NSK + kt * 64 + m;
      out[(size_t)NB * NSQ * NSK + o] = softplus_(vpart + bv2p[0]);
    }
    if (t < 256) { sB2[t] = b2[t]; sB3[t] = b3[t]; sWf[t] = Wf[t]; }
  }
  __syncthreads();

  // --- GEMM1: D1[n][m] = sum_k W2[k][n] * X1[m][k], A double-buffered ---
  f32x4 acc[2][4];
  #pragma unroll
  for (int ft = 0; ft < 2; ++ft)
    #pragma unroll
    for (int pt = 0; pt < 4; ++pt)
      acc[ft][pt] = (f32x4){0.f, 0.f, 0.f, 0.f};

  #pragma unroll
  for (int s = 0; s < 8; ++s) {
    if (s < 7) {
      afd[(s + 1) & 1][0] = *(const f16x8*)(a2base + (size_t)(s + 1) * 512);
      afd[(s + 1) & 1][1] = *(const f16x8*)(a2base + 8 * 64 * 8 + (size_t)(s + 1) * 512);
    }
    f16x8 bfr[4];
    #pragma unroll
    for (int pt = 0; pt < 4; ++pt) {
      const int chunk = ((s << 2) + q4) ^ lsw;
      bfr[pt] = *(const f16x8*)&sXH[(pt * 16 + l15) * 256 + chunk * 8];
    }
    #pragma unroll
    for (int ft = 0; ft < 2; ++ft)
      #pragma unroll
      for (int pt = 0; pt < 4; ++pt)
        acc[ft][pt] = __builtin_amdgcn_mfma_f32_16x16x32_f16(afd[s & 1][ft], bfr[pt], acc[ft][pt], 0, 0, 0);
  }
  __syncthreads();   // all X1 reads done before overwrite

  // Prefetch GEMM2 s=0 A-frags during epilogue 1.
  afd[0][0] = *(const f16x8*)(a3base);
  afd[0][1] = *(const f16x8*)(a3base + 8 * 64 * 8);

  // --- Epilogue 1: H1 = relu(D1 + b2) -> f16, same LDS buffer (swizzled) ---
  #pragma unroll
  for (int ft = 0; ft < 2; ++ft) {
    const int tg = wave * 2 + ft;
    const int n0 = tg * 16 + q4 * 4;
    float4 b4 = *(const float4*)&sB2[n0];
    const int chunkS = ((n0 >> 3) ^ lsw);
    #pragma unroll
    for (int pt = 0; pt < 4; ++pt) {
      const int mr = pt * 16 + l15;
      f32x4 a = acc[ft][pt];
      ushort2 lo = f2h2(relu_(a[0] + b4.x), relu_(a[1] + b4.y));
      ushort2 hi = f2h2(relu_(a[2] + b4.z), relu_(a[3] + b4.w));
      ushort4 h; h.x = lo.x; h.y = lo.y; h.z = hi.x; h.w = hi.y;
      *(ushort4*)&sXH[mr * 256 + chunkS * 8 + (n0 & 7)] = h;
    }
  }
  __syncthreads();

  // --- GEMM2: D2[n][m] = sum_k W3[k][n] * H1[m][k], A double-buffered ---
  f32x4 acc2[2][4];
  #pragma unroll
  for (int ft = 0; ft < 2; ++ft)
    #pragma unroll
    for (int pt = 0; pt < 4; ++pt)
      acc2[ft][pt] = (f32x4){0.f, 0.f, 0.f, 0.f};

  #pragma unroll
  for (int s = 0; s < 8; ++s) {
    if (s < 7) {
      afd[(s + 1) & 1][0] = *(const f16x8*)(a3base + (size_t)(s + 1) * 512);
      afd[(s + 1) & 1][1] = *(const f16x8*)(a3base + 8 * 64 * 8 + (size_t)(s + 1) * 512);
    }
    f16x8 bfr[4];
    #pragma unroll
    for (int pt = 0; pt < 4; ++pt) {
      const int chunk = ((s << 2) + q4) ^ lsw;
      bfr[pt] = *(const f16x8*)&sXH[(pt * 16 + l15) * 256 + chunk * 8];
    }
    #pragma unroll
    for (int ft = 0; ft < 2; ++ft)
      #pragma unroll
      for (int pt = 0; pt < 4; ++pt)
        acc2[ft][pt] = __builtin_amdgcn_mfma_f32_16x16x32_f16(afd[s & 1][ft], bfr[pt], acc2[ft][pt], 0, 0, 0);
  }

  // --- Final epilogue: logit partials over this wave's 32 n-cols ---
  float p[4] = {0.f, 0.f, 0.f, 0.f};
  #pragma unroll
  for (int ft = 0; ft < 2; ++ft) {
    const int tg = wave * 2 + ft;
    const int n0 = tg * 16 + q4 * 4;
    float4 b4 = *(const float4*)&sB3[n0];
    float4 w4 = *(const float4*)&sWf[n0];
    #pragma unroll
    for (int pt = 0; pt < 4; ++pt) {
      f32x4 a = acc2[ft][pt];
      p[pt] += relu_(a[0] + b4.x) * w4.x + relu_(a[1] + b4.y) * w4.y
             + relu_(a[2] + b4.z) * w4.z + relu_(a[3] + b4.w) * w4.w;
    }
  }
  __syncthreads();   // sB2/sB3 reads done before sRed (alias) writes
  #pragma unroll
  for (int pt = 0; pt < 4; ++pt) {
    float v = p[pt];
    v += __shfl_xor(v, 16, 64);
    v += __shfl_xor(v, 32, 64);
    if (lane < 16) sRed[wave * 64 + pt * 16 + lane] = v;
  }
  __syncthreads();

  if (t < 64) {
    const size_t o = (size_t)(bz * NSQ + qy) * NSK + kt * 64 + t;
    float lg = bfp[0];
    #pragma unroll
    for (int w = 0; w < 8; ++w) lg += sRed[w * 64 + t];
    out[o] = lg;
  }
}

// ---------------------------------------------------------------------------
extern "C" void kernel_launch(void* const* d_in, const int* in_sizes, int n_in,
                              void* d_out, int out_size, void* d_ws, size_t ws_size,
                              hipStream_t stream)
{
  (void)in_sizes; (void)n_in; (void)out_size; (void)ws_size;
  const float* query = (const float*)d_in[0];
  const float* key   = (const float*)d_in[1];
  const float* Wqe   = (const float*)d_in[2];
  const float* bqe   = (const float*)d_in[3];
  const float* Wke   = (const float*)d_in[4];
  const float* bke   = (const float*)d_in[5];
  const float* W1    = (const float*)d_in[6];
  const float* b1    = (const float*)d_in[7];
  const float* W2    = (const float*)d_in[8];
  const float* b2    = (const float*)d_in[9];
  const float* W3    = (const float*)d_in[10];
  const float* b3    = (const float*)d_in[11];
  const float* Wf    = (const float*)d_in[12];
  const float* bf    = (const float*)d_in[13];
  const float* Wv1   = (const float*)d_in[14];
  const float* bv1   = (const float*)d_in[15];
  const float* Wv2   = (const float*)d_in[16];
  const float* bv2   = (const float*)d_in[17];

  unsigned short* wsb = (unsigned short*)d_ws;
  _Float16* Pq = (_Float16*)((char*)d_ws + F16_WS_END_BYTES);   // [1024][512] f16
  _Float16* Pk = Pq + (size_t)1024 * 512;                       // [1024][512] f16
  float* out = (float*)d_out;

  shuffle_weights<<<1281, 64, 0, stream>>>(Wqe, Wke, W1, Wv1, W2, W3, Wv2, wsb);
  encoder_kernel<<<64, 256, 0, stream>>>(query, key, bqe, bke, b1, bv1,
      wsb + OFF_WQEF, wsb + OFF_WKEF, wsb + OFF_WCQ, wsb + OFF_WCK, Pq, Pk);
  pair_kernel<<<dim3(NSK / 64, NSQ, NB), 512, 0, stream>>>(Pq, Pk,
      wsb + OFF_W2F, wsb + OFF_W3F, b2, b3, Wf, bf, wsb + OFF_WV2H, bv2, out);
}